// Round 7
// baseline (287.655 us; speedup 1.0000x reference)
//
#include <hip/hip_runtime.h>
#include <cstdint>

typedef __attribute__((ext_vector_type(8))) short short8;
typedef __attribute__((ext_vector_type(4))) float floatx4;
typedef __attribute__((ext_vector_type(8))) int intx8;

__device__ __forceinline__ unsigned short f2bf(float f) {
  unsigned int u = __float_as_uint(f);
  u += 0x7fffu + ((u >> 16) & 1u);   // RNE, finite inputs
  return (unsigned short)(u >> 16);
}

// ---------------- GroupNorm partial sums: 1024 blocks ----------------------
__global__ __launch_bounds__(256) void gn_partial_kernel(
    const float* __restrict__ x, float* __restrict__ gsums) {
  const int b = blockIdx.x >> 8;
  const int g = (blockIdx.x >> 3) & 31;
  const int e = blockIdx.x & 7;
  const long long off = ((long long)(b * 512 + g * 16)) * 4096;
  const float4* xp = (const float4*)(x + off) + e * 2048;
  float s = 0.f, ss = 0.f;
  for (int i = threadIdx.x; i < 2048; i += 256) {
    float4 v = xp[i];
    s  += v.x + v.y + v.z + v.w;
    ss += v.x * v.x + v.y * v.y + v.z * v.z + v.w * v.w;
  }
  for (int off2 = 32; off2; off2 >>= 1) { s += __shfl_down(s, off2); ss += __shfl_down(ss, off2); }
  __shared__ float sb[8];
  const int lane = threadIdx.x & 63, wave = threadIdx.x >> 6;
  if (lane == 0) { sb[wave] = s; sb[4 + wave] = ss; }
  __syncthreads();
  if (threadIdx.x == 0) {
    atomicAdd(gsums + (b * 32 + g) * 2,     sb[0] + sb[1] + sb[2] + sb[3]);
    atomicAdd(gsums + (b * 32 + g) * 2 + 1, sb[4] + sb[5] + sb[6] + sb[7]);
  }
}

// ---------------- GroupNorm finalize: scale/shift per (b,c) ----------------
__global__ __launch_bounds__(256) void gn_finalize_kernel(
    const float* __restrict__ gsums, const float* __restrict__ gamma,
    const float* __restrict__ beta, float* __restrict__ scale,
    float* __restrict__ shift) {
  const int i = blockIdx.x * 256 + threadIdx.x;  // 0..2047
  const int b = i >> 9;
  const int c = i & 511;
  const int g = c >> 4;
  const float S  = gsums[(b * 32 + g) * 2];
  const float SS = gsums[(b * 32 + g) * 2 + 1];
  const float mean = S * (1.f / 65536.f);
  const float var  = SS * (1.f / 65536.f) - mean * mean;
  const float inv  = rsqrtf(var + 1e-5f);
  const float sc = gamma[c] * inv;
  scale[i] = sc;
  shift[i] = beta[c] - mean * sc;
}

// -------- weights fp32 -> bf16, fused with scratch zeroing -----------------
__global__ __launch_bounds__(256) void wcvt_zero_kernel(
    const float* __restrict__ wq, const float* __restrict__ wk,
    const float* __restrict__ wv, unsigned short* __restrict__ w16,
    float* __restrict__ zp, int nzero) {
  const int gi = blockIdx.x * 256 + threadIdx.x;
  if (gi < 196608) {
    const int m = gi >> 16;            // 0..2
    const int i = gi & 65535;          // *4 elems
    const float* src = (m == 0) ? wq : (m == 1) ? wk : wv;
    float4 v = *((const float4*)src + i);
    ushort4 o;
    o.x = f2bf(v.x); o.y = f2bf(v.y); o.z = f2bf(v.z); o.w = f2bf(v.w);
    *((ushort4*)(w16 + (long long)m * 262144) + i) = o;
  } else {
    const int zi = gi - 196608;
    if (zi < nzero) zp[zi] = 0.f;
  }
}

// -------- normalize + transpose: x (B,C,N) fp32 -> xnt (B,N,C) bf16 --------
__global__ __launch_bounds__(256) void norm_transpose_kernel(
    const float* __restrict__ x, const float* __restrict__ scale,
    const float* __restrict__ shift, unsigned short* __restrict__ xnt) {
  const int b = blockIdx.z;
  const int n0 = blockIdx.x * 64;
  const int c0 = blockIdx.y * 64;
  const int t = threadIdx.x;
  __shared__ unsigned short tile[64][65];
  {
    const int cl = t >> 2;
    const int nc = (t & 3) * 16;
    const int c = c0 + cl;
    const float* xp = x + ((long long)b * 512 + c) * 4096 + n0 + nc;
    const float sc = scale[b * 512 + c];
    const float sh = shift[b * 512 + c];
#pragma unroll
    for (int j = 0; j < 16; j += 4) {
      float4 v = *(const float4*)(xp + j);
      tile[cl][nc + j + 0] = f2bf(v.x * sc + sh);
      tile[cl][nc + j + 1] = f2bf(v.y * sc + sh);
      tile[cl][nc + j + 2] = f2bf(v.z * sc + sh);
      tile[cl][nc + j + 3] = f2bf(v.w * sc + sh);
    }
  }
  __syncthreads();
  {
    const int nl = t >> 2;
    const int cc = (t & 3) * 16;
    union { unsigned short u[16]; uint4 q[2]; } o;
#pragma unroll
    for (int j = 0; j < 16; ++j) o.u[j] = tile[cc + j][nl];
    unsigned short* op = xnt + ((long long)b * 4096 + n0 + nl) * 512 + c0 + cc;
    *((uint4*)op) = o.q[0];
    *((uint4*)op + 1) = o.q[1];
  }
}

// ---------------- TN GEMM (bf16), m97 structure + LDS xor-swizzle ----------
// C[m,n] = sum_k A[m*lda+k] * B[n*ldb+k]
// EPI: 3 = fp8 e4m3 out row-major [m][n], bias[m]; C u8, ldc/sC bytes.
//      6 = QK-proj: fp8 e4m3 out TRANSPOSED (rows=col-dim tokens), bias[m]
//          split bias/bias2 at m=512; C treated as u8, ldc/sC in bytes.
template <int EPI>
__global__ __launch_bounds__(256) void gemm_tn_kernel(
    const unsigned short* __restrict__ A, const unsigned short* __restrict__ B,
    void* __restrict__ C, const float* __restrict__ bias,
    const float* __restrict__ bias2,
    int lda, int ldb, int ldc, int K,
    long long sA, long long sB, long long sC) {
  const int tid = threadIdx.x;
  const int lane = tid & 63;
  const int wave = tid >> 6;
  const int m0 = blockIdx.x * 128;
  const int n0 = blockIdx.y * 128;
  const int bz = blockIdx.z;
  A += (long long)bz * sA;
  B += (long long)bz * sB;

  __shared__ unsigned short smem[17408];  // 34816 B
  unsigned short* As = smem;
  unsigned short* Bs = smem + 8192;

  floatx4 acc[4][4];
#pragma unroll
  for (int i = 0; i < 4; ++i)
#pragma unroll
    for (int j = 0; j < 4; ++j) acc[i][j] = (floatx4){0.f, 0.f, 0.f, 0.f};

  const unsigned short* ag[4];
  const unsigned short* bg[4];
  unsigned ldsoff[4];
#pragma unroll
  for (int i = 0; i < 4; ++i) {
    const int idx = i * 256 + tid;   // 16B granule within 128x64 tile
    const int r = idx >> 3;
    const int g = idx & 7;
    const int gs = g ^ (r & 7);      // xor-swizzled global granule
    ag[i] = A + (long long)(m0 + r) * lda + gs * 8;
    bg[i] = B + (long long)(n0 + r) * ldb + gs * 8;
    ldsoff[i] = (unsigned)(i * 256 + wave * 64) * 8;
  }

  const int l15 = lane & 15;
  const int wm = (wave >> 1) * 64;
  const int wn = (wave & 1) * 64;

  for (int k0 = 0; k0 < K; k0 += 64) {
#pragma unroll
    for (int i = 0; i < 4; ++i) {
      __builtin_amdgcn_global_load_lds(
          (const __attribute__((address_space(1))) void*)(ag[i] + k0),
          (__attribute__((address_space(3))) void*)(As + ldsoff[i]), 16, 0, 0);
      __builtin_amdgcn_global_load_lds(
          (const __attribute__((address_space(1))) void*)(bg[i] + k0),
          (__attribute__((address_space(3))) void*)(Bs + ldsoff[i]), 16, 0, 0);
    }
    __syncthreads();
#pragma unroll
    for (int kk = 0; kk < 64; kk += 32) {
      const int gq = (kk >> 3) + (lane >> 4);
      short8 af[4], bfr[4];
#pragma unroll
      for (int mt = 0; mt < 4; ++mt) {
        const int row = wm + mt * 16 + l15;
        af[mt] = *(const short8*)&As[row * 64 + ((gq ^ (row & 7)) << 3)];
      }
#pragma unroll
      for (int nt = 0; nt < 4; ++nt) {
        const int row = wn + nt * 16 + l15;
        bfr[nt] = *(const short8*)&Bs[row * 64 + ((gq ^ (row & 7)) << 3)];
      }
#pragma unroll
      for (int mt = 0; mt < 4; ++mt)
#pragma unroll
        for (int nt = 0; nt < 4; ++nt)
          acc[mt][nt] = __builtin_amdgcn_mfma_f32_16x16x32_bf16(
              af[mt], bfr[nt], acc[mt][nt], 0, 0, 0);
    }
    __syncthreads();
  }
  // After final barrier, smem is reusable.

  const int r0 = (lane >> 4) * 4;

  if (EPI == 6) {
    // D row (r-quad) = output channel o (A=weights), col (l15) = token.
    unsigned char* t8 = (unsigned char*)smem;
    const float* bp = (m0 >= 512) ? bias2 : bias;
    const int mb = m0 & 511;
#pragma unroll
    for (int mt = 0; mt < 4; ++mt) {
      const int ml = wm + mt * 16 + r0;   // o-local, multiple of 4
      const float b0 = bp[mb + ml], b1 = bp[mb + ml + 1];
      const float b2 = bp[mb + ml + 2], b3 = bp[mb + ml + 3];
      const int gw = ml >> 4;
      const int mby = ml & 15;
#pragma unroll
      for (int nt = 0; nt < 4; ++nt) {
        const int nl = wn + nt * 16 + l15;  // token-local
        int p = __builtin_amdgcn_cvt_pk_fp8_f32(acc[mt][nt][0] + b0,
                                                acc[mt][nt][1] + b1, 0, false);
        p = __builtin_amdgcn_cvt_pk_fp8_f32(acc[mt][nt][2] + b2,
                                            acc[mt][nt][3] + b3, p, true);
        *(int*)&t8[nl * 128 + ((gw ^ (nl & 7)) << 4) + mby] = p;
      }
    }
    __syncthreads();
    unsigned char* o8 = (unsigned char*)C + (long long)bz * sC;
#pragma unroll
    for (int t = 0; t < 4; ++t) {
      const int gid = t * 256 + tid;
      const int row = gid >> 3;    // token 0..127
      const int gc = gid & 7;
      uint4 v = *(const uint4*)&t8[row * 128 + ((gc ^ (row & 7)) << 4)];
      *(uint4*)&o8[(long long)(n0 + row) * ldc + m0 + gc * 16] = v;
    }
    return;
  }

  if (EPI == 3) {
    // fp8 out, row-major [m][n] (V: rows=c, cols=token), bias[m].
    unsigned char* t8 = (unsigned char*)smem;   // [128][144] u8
#pragma unroll
    for (int mt = 0; mt < 4; ++mt) {
      const int ml = wm + mt * 16 + r0;
      const float b0 = bias[m0 + ml],     b1 = bias[m0 + ml + 1];
      const float b2 = bias[m0 + ml + 2], b3 = bias[m0 + ml + 3];
#pragma unroll
      for (int nt = 0; nt < 4; ++nt) {
        const int nl = wn + nt * 16 + l15;
        int p0 = __builtin_amdgcn_cvt_pk_fp8_f32(acc[mt][nt][0] + b0,
                                                 acc[mt][nt][1] + b1, 0, false);
        int p1 = __builtin_amdgcn_cvt_pk_fp8_f32(acc[mt][nt][2] + b2,
                                                 acc[mt][nt][3] + b3, 0, false);
        t8[(ml + 0) * 144 + nl] = (unsigned char)(p0 & 0xff);
        t8[(ml + 1) * 144 + nl] = (unsigned char)((p0 >> 8) & 0xff);
        t8[(ml + 2) * 144 + nl] = (unsigned char)(p1 & 0xff);
        t8[(ml + 3) * 144 + nl] = (unsigned char)((p1 >> 8) & 0xff);
      }
    }
    __syncthreads();
    unsigned char* o8 = (unsigned char*)C + (long long)bz * sC;
#pragma unroll
    for (int t = 0; t < 4; ++t) {
      const int gid = t * 256 + tid;
      const int row = gid >> 3;    // m-local 0..127
      const int gc = gid & 7;
      uint4 v = *(const uint4*)&t8[row * 144 + gc * 16];
      *(uint4*)&o8[(long long)(m0 + row) * ldc + n0 + gc * 16] = v;
    }
    return;
  }
}

// -------- Fused attention: out[c,n] = x[c,n] + V.softmax(QK^T)/lsum --------
// One block = 64-token Q-tile (n0..n0+63) of batch bz; j-loop 32 x 128 keys.
// 512 threads / 8 waves. Q (64x512) + K_j (128x512) in swizzled LDS;
// P (64x144 fp8) LDS hand-off; V A-frags register-direct from L2.
// lsum accumulated locally (no atomics / global lsum).
// Grid 256 = 1 block/CU. XCD decode: each XCD's 32 blocks share one batch
// (K,V both 2 MB -> L2-resident per XCD).
__global__ __launch_bounds__(512, 1) void fused_attn_kernel(
    const unsigned char* __restrict__ qk8,  // (B,N,1024) fp8: [q ; k]
    const unsigned char* __restrict__ vv8,  // (B,C,N) fp8, row stride 4096 B
    float* __restrict__ out, const float* __restrict__ res) {
  const int id = blockIdx.x;
  const int xcd = id & 7;
  const int slot = id >> 3;                  // 0..31
  const int bz = xcd & 3;
  const int n0 = ((xcd >> 2) * 32 + slot) * 64;

  const unsigned char* Q = qk8 + (long long)bz * (4096LL * 1024);
  const unsigned char* K = Q + 512;
  const unsigned char* V = vv8 + (long long)bz * (512LL * 4096);

  const int tid = threadIdx.x;
  const int lane = tid & 63;
  const int wave = tid >> 6;                 // 0..7
  const int l15 = lane & 15;
  const int quad = lane >> 4;

  __shared__ unsigned char smem[109568];
  unsigned char* Qs = smem;                  // 64 x 512, swizzled
  unsigned char* Ks = smem + 32768;          // 128 x 512, swizzled
  unsigned char* Ps = smem + 98304;          // 64 x 144
  float* red = (float*)(smem + 107520);      // 8 x 64

  floatx4 acc[4][4];                         // [c-sub][n-sub]
#pragma unroll
  for (int i = 0; i < 4; ++i)
#pragma unroll
    for (int j = 0; j < 4; ++j) acc[i][j] = (floatx4){0.f, 0.f, 0.f, 0.f};
  float rs[4] = {0.f, 0.f, 0.f, 0.f};        // lsum partials, n = ns*16+l15

#define FA_GLDS(gp, lp)                                              \
  __builtin_amdgcn_global_load_lds(                                  \
      (const __attribute__((address_space(1))) void*)(gp),           \
      (__attribute__((address_space(3))) void*)(lp), 16, 0, 0)

  // Staging descriptors. 512-B rows = 32 granules; swizzle low 3 bits.
  const unsigned char* kg[8];
  unsigned ko[8];
#pragma unroll
  for (int j = 0; j < 8; ++j) {
    const int idx = j * 512 + tid;           // K granule 0..4095
    const int r = idx >> 5;                  // row 0..127
    const int g = idx & 31;
    const int gs = (g & 24) | ((g & 7) ^ (r & 7));
    kg[j] = K + (long long)r * 1024 + gs * 16;
    ko[j] = 32768u + (unsigned)(j * 512 + wave * 64) * 16;
  }
  {
    // Q stage (once): 2048 granules, 4/thread
#pragma unroll
    for (int j = 0; j < 4; ++j) {
      const int idx = j * 512 + tid;
      const int r = idx >> 5;                // row 0..63
      const int g = idx & 31;
      const int gs = (g & 24) | ((g & 7) ^ (r & 7));
      FA_GLDS(Q + (long long)(n0 + r) * 1024 + gs * 16,
              smem + (unsigned)(j * 512 + wave * 64) * 16);
    }
    // K tile 0
#pragma unroll
    for (int j = 0; j < 8; ++j) FA_GLDS(kg[j], smem + ko[j]);
    asm volatile("s_waitcnt vmcnt(0)" ::: "memory");
    __builtin_amdgcn_s_barrier();
  }

  // V frag base addresses: row c = wave*64 + cs*16 + l15, chunk quad*32
  const unsigned char* vg[4];
#pragma unroll
  for (int cs = 0; cs < 4; ++cs)
    vg[cs] = V + (long long)(wave * 64 + cs * 16 + l15) * 4096 + quad * 32;

  const float SCL = 0.044194173824159216f;   // 1/sqrt(512)

  for (int t = 0; t < 32; ++t) {
    const int jcol = t * 128;

    // ---- V_t A-frags: register-direct from L2 (issued early) ----
    uint4 vf[4][2];
#pragma unroll
    for (int cs = 0; cs < 4; ++cs) {
      vf[cs][0] = *(const uint4*)(vg[cs] + jcol);
      vf[cs][1] = *(const uint4*)(vg[cs] + jcol + 16);
    }
    __builtin_amdgcn_sched_barrier(0);

    // ---- QK: S[16j x 64n] per wave (wave = j-stripe) ----
    floatx4 sacc[4];
#pragma unroll
    for (int ns = 0; ns < 4; ++ns) sacc[ns] = (floatx4){0.f, 0.f, 0.f, 0.f};
#pragma unroll
    for (int kc = 0; kc < 4; ++kc) {
      intx8 af;
      {
        const int row = wave * 16 + l15;     // K row (j-local)
        const int r7 = row & 7;
        const uint4 x0 = *(const uint4*)(Ks + row * 512 + kc * 128 +
                                         (((2 * quad) ^ r7) << 4));
        const uint4 x1 = *(const uint4*)(Ks + row * 512 + kc * 128 +
                                         (((2 * quad + 1) ^ r7) << 4));
        af = (intx8){(int)x0.x, (int)x0.y, (int)x0.z, (int)x0.w,
                     (int)x1.x, (int)x1.y, (int)x1.z, (int)x1.w};
      }
#pragma unroll
      for (int ns = 0; ns < 4; ++ns) {
        const int row = ns * 16 + l15;       // Q row (n-local)
        const int r7 = row & 7;
        const uint4 x0 = *(const uint4*)(Qs + row * 512 + kc * 128 +
                                         (((2 * quad) ^ r7) << 4));
        const uint4 x1 = *(const uint4*)(Qs + row * 512 + kc * 128 +
                                         (((2 * quad + 1) ^ r7) << 4));
        const intx8 bq = (intx8){(int)x0.x, (int)x0.y, (int)x0.z, (int)x0.w,
                                 (int)x1.x, (int)x1.y, (int)x1.z, (int)x1.w};
        sacc[ns] = __builtin_amdgcn_mfma_scale_f32_16x16x128_f8f6f4(
            af, bq, sacc[ns], 0, 0, 0, 127, 0, 127);
      }
    }

    // ---- exp + pack fp8 + P write; accumulate local lsum ----
#pragma unroll
    for (int ns = 0; ns < 4; ++ns) {
      const float e0 = __expf(sacc[ns][0] * SCL);
      const float e1 = __expf(sacc[ns][1] * SCL);
      const float e2 = __expf(sacc[ns][2] * SCL);
      const float e3 = __expf(sacc[ns][3] * SCL);
      rs[ns] += e0 + e1 + e2 + e3;
      int p = __builtin_amdgcn_cvt_pk_fp8_f32(e0, e1, 0, false);
      p = __builtin_amdgcn_cvt_pk_fp8_f32(e2, e3, p, true);
      *(int*)&Ps[(ns * 16 + l15) * 144 + wave * 16 + quad * 4] = p;
    }
    asm volatile("s_waitcnt lgkmcnt(0)" ::: "memory");
    __builtin_amdgcn_sched_barrier(0);
    __builtin_amdgcn_s_barrier();            // P ready; Ks free (all reads done)

    // ---- stage K_{t+1} into the (single) K buffer ----
    if (t < 31) {
      const long long koff = (long long)(t + 1) * 131072;   // 128 rows x 1024B
#pragma unroll
      for (int j = 0; j < 8; ++j) FA_GLDS(kg[j] + koff, smem + ko[j]);
    }
    __builtin_amdgcn_sched_barrier(0);

    // ---- PV: acc[c-sub][n-sub] += V_j x P^T (K = 128) ----
    intx8 pb[4];
#pragma unroll
    for (int ns = 0; ns < 4; ++ns) {
      const int row = ns * 16 + l15;         // P row (n-local)
      const uint4 x0 = *(const uint4*)(Ps + row * 144 + quad * 32);
      const uint4 x1 = *(const uint4*)(Ps + row * 144 + quad * 32 + 16);
      pb[ns] = (intx8){(int)x0.x, (int)x0.y, (int)x0.z, (int)x0.w,
                       (int)x1.x, (int)x1.y, (int)x1.z, (int)x1.w};
    }
    __builtin_amdgcn_s_setprio(1);
#pragma unroll
    for (int cs = 0; cs < 4; ++cs) {
      const intx8 av = (intx8){(int)vf[cs][0].x, (int)vf[cs][0].y,
                               (int)vf[cs][0].z, (int)vf[cs][0].w,
                               (int)vf[cs][1].x, (int)vf[cs][1].y,
                               (int)vf[cs][1].z, (int)vf[cs][1].w};
#pragma unroll
      for (int ns = 0; ns < 4; ++ns)
        acc[cs][ns] = __builtin_amdgcn_mfma_scale_f32_16x16x128_f8f6f4(
            av, pb[ns], acc[cs][ns], 0, 0, 0, 127, 0, 127);
    }
    __builtin_amdgcn_s_setprio(0);

    // K_{t+1} landed before next iter's LDS reads (cross-wave: drain+barrier)
    asm volatile("s_waitcnt vmcnt(0)" ::: "memory");
    __builtin_amdgcn_s_barrier();
  }
#undef FA_GLDS

  // ---- lsum reduce: quad-reduce, per-wave partials, cross-wave sum ----
#pragma unroll
  for (int ns = 0; ns < 4; ++ns) {
    float r = rs[ns];
    r += __shfl_xor(r, 16);
    r += __shfl_xor(r, 32);
    if (quad == 0) red[wave * 64 + ns * 16 + l15] = r;
  }
  __syncthreads();
  float inv[4];
#pragma unroll
  for (int ns = 0; ns < 4; ++ns) {
    float s = 0.f;
#pragma unroll
    for (int w = 0; w < 8; ++w) s += red[w * 64 + ns * 16 + l15];
    inv[ns] = 1.f / s;
  }

  // ---- epilogue: out[c][n] = acc/lsum + x ----
  float* o = out + (long long)bz * (4096LL * 512);
  const float* rr = res + (long long)bz * (4096LL * 512);
#pragma unroll
  for (int cs = 0; cs < 4; ++cs) {
#pragma unroll
    for (int ns = 0; ns < 4; ++ns) {
      const int n = n0 + ns * 16 + l15;
#pragma unroll
      for (int r = 0; r < 4; ++r) {
        const int c = wave * 64 + cs * 16 + quad * 4 + r;
        const long long off = (long long)c * 4096 + n;
        o[off] = acc[cs][ns][r] * inv[ns] + rr[off];
      }
    }
  }
}

extern "C" void kernel_launch(void* const* d_in, const int* in_sizes, int n_in,
                              void* d_out, int out_size, void* d_ws, size_t ws_size,
                              hipStream_t stream) {
  const float* x     = (const float*)d_in[0];
  const float* gamma = (const float*)d_in[1];
  const float* beta  = (const float*)d_in[2];
  const float* wq    = (const float*)d_in[3];
  const float* bq    = (const float*)d_in[4];
  const float* wk    = (const float*)d_in[5];
  const float* bk    = (const float*)d_in[6];
  const float* wv    = (const float*)d_in[7];
  const float* bv    = (const float*)d_in[8];
  float* out = (float*)d_out;

  const long long sTok = 4096LL * 512;     // per-batch token-major elems
  const long long sQK8 = 4096LL * 1024;    // per-batch qk8 bytes
  const long long sV8  = 512LL * 4096;     // per-batch V fp8 bytes

  char* ws = (char*)d_ws;
  float* scale = (float*)ws;                                // 8 KB
  float* shift = (float*)(ws + 8192);                       // 8 KB
  unsigned short* w16 = (unsigned short*)(ws + 16384);      // [wq;wk;wv] bf16
  unsigned short* xnt = (unsigned short*)(ws + 1589248);    // (B,N,C) bf16
  unsigned char*  qk8 = (unsigned char*)(ws + 18366464);    // (B,N,1024) fp8
  unsigned char*  vv8 = (unsigned char*)(ws + 51920896);    // (B,C,N) fp8
  float* gsums = (float*)(ws + 60317696);                   // 256 floats

  // wcvt (768 blocks) + zero gsums (1 tail block), one launch
  wcvt_zero_kernel<<<769, 256, 0, stream>>>(wq, wk, wv, w16, gsums, 256);
  gn_partial_kernel<<<1024, 256, 0, stream>>>(x, gsums);
  gn_finalize_kernel<<<8, 256, 0, stream>>>(gsums, gamma, beta, scale, shift);
  norm_transpose_kernel<<<dim3(64, 8, 4), 256, 0, stream>>>(x, scale, shift, xnt);

  // QK-proj -> fp8: qk8[token][o], o in [0,1024) = [q ; k]
  gemm_tn_kernel<6><<<dim3(8, 32, 4), 256, 0, stream>>>(
      w16, xnt, qk8, bq, bk, 512, 512, 1024, 512, 0, sTok, sQK8);
  // V: (B,C,N) = Wv * Xn  (fp8 e4m3, row-major c, ldc bytes)
  gemm_tn_kernel<3><<<dim3(4, 32, 4), 256, 0, stream>>>(
      w16 + 524288, xnt, vv8, bv, nullptr, 512, 512, 4096, 512, 0, sTok, sV8);

  // Fused S+PV: no S / lsum materialization.
  fused_attn_kernel<<<256, 512, 0, stream>>>(qk8, vv8, out, x);
}